// Round 8
// baseline (159.852 us; speedup 1.0000x reference)
//
#include <hip/hip_runtime.h>

#define NB 4
#define NC 32
#define H0 64
#define W0 128
#define D0 12
#define H1 128
#define W1 256
#define NK 5
#define IMH 512
#define IMW 1024

#define S0 148   // frs0 row stride (16 guard + 128 data + 4 pad), 16B-aligned
#define G0 16
#define S1 292   // frs1 row stride (28 guard + 256 data + 4 rguard + 4 pad)
#define G1 28

#define GRID 256

// monotonic device-scope grid barrier (cooperative-groups recipe, by hand)
__device__ __forceinline__ void gbar(int* cnt, int target) {
    __syncthreads();
    __threadfence();
    if (threadIdx.x == 0) {
        __hip_atomic_fetch_add(cnt, 1, __ATOMIC_ACQ_REL, __HIP_MEMORY_SCOPE_AGENT);
        while (__hip_atomic_load(cnt, __ATOMIC_ACQUIRE, __HIP_MEMORY_SCOPE_AGENT) < target) {
            __builtin_amdgcn_s_sleep(2);
        }
    }
    __syncthreads();
    __threadfence();
}

__global__ __launch_bounds__(512, 4) void k_fused(
        const float* __restrict__ fl0, const float* __restrict__ fr0,
        const float* __restrict__ fl1, const float* __restrict__ fr1,
        float* pl0, float* pl1, float* __restrict__ out, int* gcnt) {
    const int bk = blockIdx.x;           // 0..255
    const int tid = threadIdx.x;         // 0..511
    __shared__ float smem[9728];         // 38 KB union

    // ======================= phase 1: scale-0 cost volume ====================
    {
        float (*frs)[S0] = (float(*)[S0])smem;
        const int r = bk;                // b*H0 + h
        const int b = r >> 6, h = r & (H0 - 1);
        const size_t rowbase = ((size_t)b * NC * H0 + h) * W0;

        const int w = tid >> 2, g = tid & 3;     // 128 w x 4 groups

        // prefetch fl (8 channels: c = 4j+g)
        float flv[8];
#pragma unroll
        for (int j = 0; j < 8; ++j)
            flv[j] = fl0[rowbase + (size_t)(4 * j + g) * (H0 * W0) + w];

        // stage fr row: data (2x512 float4, exact) + left guards (128 float4)
#pragma unroll
        for (int i = 0; i < 2; ++i) {
            int idx = i * 512 + tid;             // < 1024 = 32ch * 32 f4
            int c = idx >> 5, q = idx & 31;
            *(float4*)&frs[c][G0 + q * 4] =
                *(const float4*)(fr0 + rowbase + (size_t)c * (H0 * W0) + q * 4);
        }
        if (tid < 128) {
            int c = tid >> 2, u = tid & 3;
            *(float4*)&frs[c][u * 4] = make_float4(0.f, 0.f, 0.f, 0.f);
        }
        __syncthreads();

        float cost[D0];
#pragma unroll
        for (int d = 0; d < D0; ++d) cost[d] = 0.f;
#pragma unroll
        for (int j = 0; j < 8; ++j) {
            const float* sr = &frs[4 * j + g][G0 + w];
#pragma unroll
            for (int d = 0; d < D0; ++d)
                cost[d] += fabsf(flv[j] - sr[-d]);
        }
#pragma unroll
        for (int d = 0; d < D0; ++d) {
            cost[d] += __shfl_xor(cost[d], 1);
            cost[d] += __shfl_xor(cost[d], 2);
        }
        if (g == 0) {
            float m = cost[0];
#pragma unroll
            for (int d = 1; d < D0; ++d) m = fminf(m, cost[d]);
            float s = 0.f, sd = 0.f;
#pragma unroll
            for (int d = 0; d < D0; ++d) {
                float e = expf(m - cost[d]);
                s += e;
                sd += (float)d * e;
            }
            pl0[(size_t)r * W0 + w] = 8.f * (sd / s);
        }
    }

    gbar(gcnt, GRID);

    // ================= phase 2: wflow composite + residual cost ==============
    {
        float (*frs1)[S1] = (float(*)[S1])smem;
        float* ytmp = smem + NC * S1;            // 128
        float* wfl  = smem + NC * S1 + W0;       // 256

        for (int it = 0; it < 2; ++it) {
            const int rowid = bk * 2 + it;       // b*H1 + oy
            const int b = rowid >> 7, oy = rowid & (H1 - 1);
            const size_t rowbase1 = ((size_t)b * NC * H1 + oy) * W1;

            // prefetch fl1 (16 channels: c = 2j+hh)
            const int w = tid >> 1, hh = tid & 1;
            float flv[16];
#pragma unroll
            for (int j = 0; j < 16; ++j)
                flv[j] = fl1[rowbase1 + (size_t)(2 * j + hh) * (H1 * W1) + w];

            // stage fr1 row: data (4x512 float4, exact) + guards (256 float4)
#pragma unroll
            for (int i = 0; i < 4; ++i) {
                int idx = i * 512 + tid;         // < 2048 = 32ch * 64 f4
                int c = idx >> 6, q = idx & 63;
                *(float4*)&frs1[c][G1 + q * 4] =
                    *(const float4*)(fr1 + rowbase1 + (size_t)c * (H1 * W1) + q * 4);
            }
            if (tid < 256) {
                int c = tid >> 3, u = tid & 7;
                int col = (u < 7) ? (u * 4) : 284;   // left 0..27, right 284..287
                *(float4*)&frs1[c][col] = make_float4(0.f, 0.f, 0.f, 0.f);
            }

            // y-composite of pl0
            if (tid < W0) {
                const float* p0b = pl0 + (size_t)b * H0 * W0;
                int m = oy >> 1;
                int r0, r1, r2;
                float wy0, wy1, wy2;
                if (oy == 0) {
                    r0 = 0; r1 = 0; r2 = 1;
                    wy0 = 0.f; wy1 = 27.625f / 28.f; wy2 = 0.375f / 28.f;
                } else if (oy == H1 - 1) {
                    r0 = H0 - 2; r1 = H0 - 1; r2 = H0 - 1;
                    wy0 = 0.375f / 28.f; wy1 = 27.625f / 28.f; wy2 = 0.f;
                } else {
                    r0 = max(m - 1, 0); r1 = m; r2 = min(m + 1, H0 - 1);
                    if (oy & 1) { wy0 = 0.375f / 32.f; wy1 = 23.25f / 32.f; wy2 = 8.375f / 32.f; }
                    else        { wy0 = 8.375f / 32.f; wy1 = 23.25f / 32.f; wy2 = 0.375f / 32.f; }
                }
                ytmp[tid] = wy0 * p0b[r0 * W0 + tid] + wy1 * p0b[r1 * W0 + tid]
                          + wy2 * p0b[r2 * W0 + tid];
            }
            __syncthreads();

            // x-composite into wfl
            if (tid < W1) {
                int ox = tid, n = ox >> 1;
                int c0, c1, c2;
                float wx0, wx1, wx2;
                if (ox == 0) {
                    c0 = 0; c1 = 0; c2 = 1;
                    wx0 = 0.f; wx1 = 27.625f / 28.f; wx2 = 0.375f / 28.f;
                } else if (ox == W1 - 1) {
                    c0 = W0 - 2; c1 = W0 - 1; c2 = W0 - 1;
                    wx0 = 0.375f / 28.f; wx1 = 27.625f / 28.f; wx2 = 0.f;
                } else {
                    c0 = max(n - 1, 0); c1 = n; c2 = min(n + 1, W0 - 1);
                    if (ox & 1) { wx0 = 0.375f / 32.f; wx1 = 23.25f / 32.f; wx2 = 8.375f / 32.f; }
                    else        { wx0 = 8.375f / 32.f; wx1 = 23.25f / 32.f; wx2 = 0.375f / 32.f; }
                }
                wfl[ox] = 0.25f * (wx0 * ytmp[c0] + wx1 * ytmp[c1] + wx2 * ytmp[c2]);
            }
            __syncthreads();

            // residual cost: shared-frac 6-tap window
            {
                float disp = wfl[w];
                float xs = (float)w - disp;
                float xbf = floorf(xs);
                float f = xs - xbf;
                int xb = (int)xbf;               // in [w-23, w]
                const float* sr = &frs1[0][G1 + xb - 2];

                float cost[NK];
#pragma unroll
                for (int k = 0; k < NK; ++k) cost[k] = 0.f;
#pragma unroll
                for (int j = 0; j < 16; ++j) {
                    const float* row = sr + (2 * j + hh) * S1;
                    float g0 = row[0], g1 = row[1], g2 = row[2];
                    float g3 = row[3], g4 = row[4], g5 = row[5];
                    float flvj = flv[j];
                    cost[0] += fabsf(flvj - (g0 + f * (g1 - g0)));
                    cost[1] += fabsf(flvj - (g1 + f * (g2 - g1)));
                    cost[2] += fabsf(flvj - (g2 + f * (g3 - g2)));
                    cost[3] += fabsf(flvj - (g3 + f * (g4 - g3)));
                    cost[4] += fabsf(flvj - (g5 * f + g4 * (1.f - f)));
                }
#pragma unroll
                for (int k = 0; k < NK; ++k) cost[k] += __shfl_xor(cost[k], 1);
                if (hh == 0) {
                    float m = cost[0];
#pragma unroll
                    for (int k = 1; k < NK; ++k) m = fminf(m, cost[k]);
                    float s = 0.f, sd = 0.f;
#pragma unroll
                    for (int k = 0; k < NK; ++k) {
                        float e = expf(m - cost[k]);
                        s += e;
                        sd += (float)(k - 2) * e;
                    }
                    pl1[(size_t)rowid * W1 + w] = 4.f * (sd / s);
                }
            }
            __syncthreads();   // frs1/ytmp/wfl reused next iteration
        }
    }

    gbar(gcnt, 2 * GRID);

    // ================== phase 3: fused dual upsample + output ================
    {
        float* a0 = smem;            // [2][128]
        float* a1 = smem + 256;      // [2][256]
        const size_t NPXQ = (size_t)NB * IMH * IMW / 4;

#pragma unroll
        for (int i = 0; i < 4; ++i) {
            // prep y-lerped rows for 2 output rows
            {
                int lr2 = tid >> 8, col = tid & 255;
                int r2 = bk * 8 + i * 2 + lr2;
                int b2 = r2 >> 9, y2 = r2 & (IMH - 1);
                const float* p1b = pl1 + (size_t)b2 * H1 * W1;
                float sy1 = (y2 + 0.5f) * 0.25f - 0.5f;
                float y1f = floorf(sy1);
                float fy1 = sy1 - y1f;
                int s0 = (int)y1f;
                int s0c = min(max(s0, 0), H1 - 1), s1c = min(max(s0 + 1, 0), H1 - 1);
                float u = p1b[s0c * W1 + col], v = p1b[s1c * W1 + col];
                a1[lr2 * W1 + col] = u + fy1 * (v - u);
            }
            if (tid < 256) {
                int lr3 = tid >> 7, col = tid & 127;
                int r3 = bk * 8 + i * 2 + lr3;
                int b3 = r3 >> 9, y3 = r3 & (IMH - 1);
                const float* p0b = pl0 + (size_t)b3 * H0 * W0;
                float sy0 = (y3 + 0.5f) * 0.125f - 0.5f;
                float y0f = floorf(sy0);
                float fy0 = sy0 - y0f;
                int q0 = (int)y0f;
                int r0c = min(max(q0, 0), H0 - 1), r1c = min(max(q0 + 1, 0), H0 - 1);
                float u = p0b[r0c * W0 + col], v = p0b[r1c * W0 + col];
                a0[lr3 * W0 + col] = u + fy0 * (v - u);
            }
            __syncthreads();

            // x-lerp + store (2 rows x 256 float4)
            {
                int lr = tid >> 8, xq = tid & 255;
                int r = bk * 8 + i * 2 + lr;
                const float* arow0 = a0 + lr * W0;
                const float* arow1 = a1 + lr * W1;

                float v0[4], v1[4];
#pragma unroll
                for (int ii = 0; ii < 4; ++ii) {
                    int x = xq * 4 + ii;
                    float sx0 = (x + 0.5f) * 0.125f - 0.5f;
                    float x0f = floorf(sx0);
                    float fx0 = sx0 - x0f;
                    int c0 = (int)x0f;
                    int c0c = min(max(c0, 0), W0 - 1), c1c = min(max(c0 + 1, 0), W0 - 1);
                    float p0 = arow0[c0c] + fx0 * (arow0[c1c] - arow0[c0c]);

                    float sx1 = (x + 0.5f) * 0.25f - 0.5f;
                    float x1f = floorf(sx1);
                    float fx1 = sx1 - x1f;
                    int d0 = (int)x1f;
                    int d0c = min(max(d0, 0), W1 - 1), d1c = min(max(d0 + 1, 0), W1 - 1);
                    float p1 = arow1[d0c] + fx1 * (arow1[d1c] - arow1[d0c]);

                    v0[ii] = p0;
                    v1[ii] = p1 + p0;
                }
                size_t t = (size_t)r * 256 + xq;
                ((float4*)out)[t] = make_float4(v0[0], v0[1], v0[2], v0[3]);
                ((float4*)out)[NPXQ + t] = make_float4(v1[0], v1[1], v1[2], v1[3]);
            }
            __syncthreads();
        }
    }
}

extern "C" void kernel_launch(void* const* d_in, const int* in_sizes, int n_in,
                              void* d_out, int out_size, void* d_ws, size_t ws_size,
                              hipStream_t stream) {
    const float* fl0 = (const float*)d_in[0];
    const float* fr0 = (const float*)d_in[1];
    const float* fl1 = (const float*)d_in[2];
    const float* fr1 = (const float*)d_in[3];
    float* out = (float*)d_out;

    int* gcnt = (int*)d_ws;                       // bytes [0,256)
    float* pl0 = (float*)d_ws + 64;               // 32768 floats
    float* pl1 = (float*)d_ws + 64 + NB * H0 * W0; // 131072 floats

    hipMemsetAsync(d_ws, 0, 256, stream);
    k_fused<<<GRID, 512, 0, stream>>>(fl0, fr0, fl1, fr1, pl0, pl1, out, gcnt);
}

// Round 9
// 30.451 us; speedup vs baseline: 5.2494x; 5.2494x over previous
//
#include <hip/hip_runtime.h>

#define NB 4
#define NC 32
#define H0 64
#define W0 128
#define D0 12
#define H1 128
#define W1 256
#define NK 5
#define IMH 512
#define IMW 1024

#define S0L 144   // 16 guard + 128 data; %32==16 -> exact 2-way (free)
#define G0L 16
#define S1L 288   // 28 guard + 256 data + 4 right guard; %32==0 -> 2-way (free)
#define G1L 28

typedef __attribute__((address_space(3))) uint32_t as3_u32;
typedef const __attribute__((address_space(1))) uint32_t as1_u32;

// ---------------------------------------------------------------------------
// K1: per block (b, m): recompute pl0 rows m-1..m+1 locally (no cross-block
// dependency), exact 3x3 wflow composite from LDS, residual cost volume for
// oy = 2m, 2m+1. Barrier-free fusion of cost0 + wflow + cost1.
// ---------------------------------------------------------------------------
__global__ __launch_bounds__(512) void k_main(
        const float* __restrict__ fl0, const float* __restrict__ fr0,
        const float* __restrict__ fl1, const float* __restrict__ fr1,
        float* __restrict__ pl0, float* __restrict__ pl1) {
    const int bk = blockIdx.x;           // 0..255
    const int b = bk >> 6, m = bk & 63;
    const int tid = threadIdx.x;         // 0..511
    const int wave = tid >> 6, lane = tid & 63;

    __shared__ float frs1[2][NC][S1L];   // 72 KB
    __shared__ float frs0[3][NC][S0L];   // 54 KB
    __shared__ float p0l[3][W0];
    __shared__ float ytmp[2][W0];
    __shared__ float wfl[2][W1];

    // ---- 1. async global->LDS stage of fr1 for BOTH oy rows (issued first,
    //         64 rows x 1 KB; latency hides under phase 1) ----
#pragma unroll
    for (int j = 0; j < 8; ++j) {
        int idx = wave * 8 + j;
        int it = idx >> 5, c = idx & 31;
        const float* src = fr1 + ((size_t)(b * NC + c) * H1 + (2 * m + it)) * W1
                         + lane * 4;
        as3_u32* dst = (as3_u32*)&frs1[it][c][G1L];
        __builtin_amdgcn_global_load_lds((as1_u32*)src, dst, 16, 0, 0);
    }
    // guards frs1: 28 left + 4 right per (it,c); 512 float4 total
    {
        int it = tid >> 8, c = (tid >> 3) & 31, u = tid & 7;
        int col = (u < 7) ? u * 4 : (G1L + W1);
        *(float4*)&frs1[it][c][col] = make_float4(0.f, 0.f, 0.f, 0.f);
    }

    // ---- 2. stage fr0 for rows m-1..m+1 (clamped), register path ----
#pragma unroll
    for (int i = 0; i < 6; ++i) {
        int idx = i * 512 + tid;                 // < 3072 = 3*32*32
        int rr = idx >> 10, rem = idx & 1023, c = rem >> 5, q = rem & 31;
        int row = min(max(m - 1 + rr, 0), H0 - 1);
        float4 v = *(const float4*)(fr0 + ((size_t)(b * NC + c) * H0 + row) * W0
                                    + q * 4);
        *(float4*)&frs0[rr][c][G0L + q * 4] = v;
    }
    if (tid < 384) {
        int rr = tid >> 7, c = (tid >> 2) & 31, u = tid & 3;
        *(float4*)&frs0[rr][c][u * 4] = make_float4(0.f, 0.f, 0.f, 0.f);
    }

    // ---- 3. register-prefetch fl0 (3 rows x 8 ch) and fl1 (2 rows x 16 ch) --
    const int w0g = tid >> 2, g = tid & 3;       // phase-1 layout
    float flv0[3][8];
#pragma unroll
    for (int rr = 0; rr < 3; ++rr) {
        int row = min(max(m - 1 + rr, 0), H0 - 1);
#pragma unroll
        for (int j = 0; j < 8; ++j)
            flv0[rr][j] = fl0[((size_t)(b * NC + 4 * j + g) * H0 + row) * W0 + w0g];
    }
    const int w1 = tid >> 1, hh = tid & 1;       // phase-2 layout
    float flv1[2][16];
#pragma unroll
    for (int it = 0; it < 2; ++it)
#pragma unroll
        for (int j = 0; j < 16; ++j)
            flv1[it][j] = fl1[((size_t)(b * NC + 2 * j + hh) * H1 + 2 * m + it) * W1
                              + w1];
    __syncthreads();

    // ---- 4. phase 1: three pl0 rows (slot 1 == row m goes to global too) ----
#pragma unroll
    for (int rr = 0; rr < 3; ++rr) {
        float cost[D0];
#pragma unroll
        for (int d = 0; d < D0; ++d) cost[d] = 0.f;
#pragma unroll
        for (int j = 0; j < 8; ++j) {
            const float* sr = &frs0[rr][4 * j + g][G0L + w0g];
            float fv = flv0[rr][j];
#pragma unroll
            for (int d = 0; d < D0; ++d)
                cost[d] += fabsf(fv - sr[-d]);
        }
#pragma unroll
        for (int d = 0; d < D0; ++d) {
            cost[d] += __shfl_xor(cost[d], 1);
            cost[d] += __shfl_xor(cost[d], 2);
        }
        if (g == 0) {
            float mn = cost[0];
#pragma unroll
            for (int d = 1; d < D0; ++d) mn = fminf(mn, cost[d]);
            float s = 0.f, sd = 0.f;
#pragma unroll
            for (int d = 0; d < D0; ++d) {
                float e = expf(mn - cost[d]);
                s += e;
                sd += (float)d * e;
            }
            float val = 8.f * (sd / s);
            p0l[rr][w0g] = val;
            if (rr == 1)
                pl0[((size_t)b * H0 + m) * W0 + w0g] = val;
        }
    }
    __syncthreads();

    // ---- 5. wflow composite: y-stencil (slots 0..2 of p0l), then x-stencil --
    if (tid < 256) {
        int it = tid >> 7, col = tid & 127;
        int oy = 2 * m + it;
        float wy0, wy1, wy2;
        if (oy == 0)            { wy0 = 0.f;            wy1 = 27.625f / 28.f; wy2 = 0.375f / 28.f; }
        else if (oy == H1 - 1)  { wy0 = 0.375f / 28.f;  wy1 = 27.625f / 28.f; wy2 = 0.f; }
        else if (oy & 1)        { wy0 = 0.375f / 32.f;  wy1 = 23.25f / 32.f;  wy2 = 8.375f / 32.f; }
        else                    { wy0 = 8.375f / 32.f;  wy1 = 23.25f / 32.f;  wy2 = 0.375f / 32.f; }
        ytmp[it][col] = wy0 * p0l[0][col] + wy1 * p0l[1][col] + wy2 * p0l[2][col];
    }
    __syncthreads();
    {
        int it = tid >> 8, ox = tid & 255;
        int n = ox >> 1;
        int c0, c1, c2;
        float wx0, wx1, wx2;
        if (ox == 0) {
            c0 = 0; c1 = 0; c2 = 1;
            wx0 = 0.f; wx1 = 27.625f / 28.f; wx2 = 0.375f / 28.f;
        } else if (ox == W1 - 1) {
            c0 = W0 - 2; c1 = W0 - 1; c2 = W0 - 1;
            wx0 = 0.375f / 28.f; wx1 = 27.625f / 28.f; wx2 = 0.f;
        } else {
            c0 = max(n - 1, 0); c1 = n; c2 = min(n + 1, W0 - 1);
            if (ox & 1) { wx0 = 0.375f / 32.f; wx1 = 23.25f / 32.f; wx2 = 8.375f / 32.f; }
            else        { wx0 = 8.375f / 32.f; wx1 = 23.25f / 32.f; wx2 = 0.375f / 32.f; }
        }
        wfl[it][ox] = 0.25f * (wx0 * ytmp[it][c0] + wx1 * ytmp[it][c1]
                             + wx2 * ytmp[it][c2]);
    }
    __syncthreads();   // wfl ready; also drains the fr1 global_load_lds queue

    // ---- 6. phase 2: residual cost, shared-frac 6-tap window, both rows ----
#pragma unroll
    for (int it = 0; it < 2; ++it) {
        float disp = wfl[it][w1];
        float xs = (float)w1 - disp;
        float xbf = floorf(xs);
        float f = xs - xbf;
        int xb = (int)xbf;                       // in [w1-23, w1]
        const float* sr = &frs1[it][0][G1L + xb - 2];

        float cost[NK];
#pragma unroll
        for (int k = 0; k < NK; ++k) cost[k] = 0.f;
#pragma unroll
        for (int j = 0; j < 16; ++j) {
            const float* row = sr + (2 * j + hh) * S1L;
            float g0 = row[0], g1 = row[1], g2 = row[2];
            float g3 = row[3], g4 = row[4], g5 = row[5];
            float fv = flv1[it][j];
            cost[0] += fabsf(fv - (g0 + f * (g1 - g0)));
            cost[1] += fabsf(fv - (g1 + f * (g2 - g1)));
            cost[2] += fabsf(fv - (g2 + f * (g3 - g2)));
            cost[3] += fabsf(fv - (g3 + f * (g4 - g3)));
            cost[4] += fabsf(fv - (g5 * f + g4 * (1.f - f)));
        }
#pragma unroll
        for (int k = 0; k < NK; ++k) cost[k] += __shfl_xor(cost[k], 1);
        if (hh == 0) {
            float mn = cost[0];
#pragma unroll
            for (int k = 1; k < NK; ++k) mn = fminf(mn, cost[k]);
            float s = 0.f, sd = 0.f;
#pragma unroll
            for (int k = 0; k < NK; ++k) {
                float e = expf(mn - cost[k]);
                s += e;
                sd += (float)(k - 2) * e;
            }
            pl1[((size_t)b * H1 + 2 * m + it) * W1 + w1] = 4.f * (sd / s);
        }
    }
}

// ---------------------------------------------------------------------------
// K2: final — separable dual upsample, one block per output row. Write-bound.
// ---------------------------------------------------------------------------
__global__ __launch_bounds__(256, 4) void k_final(const float* __restrict__ pl0,
                                                  const float* __restrict__ pl1,
                                                  float* __restrict__ out) {
    const int blk = blockIdx.x;            // b*IMH + y
    const int b = blk >> 9, y = blk & (IMH - 1);
    const int tid = threadIdx.x;
    __shared__ float a0[W0];
    __shared__ float a1[W1];

    const float* p0b = pl0 + (size_t)b * H0 * W0;
    const float* p1b = pl1 + (size_t)b * H1 * W1;

    float sy0 = (y + 0.5f) * 0.125f - 0.5f;
    float y0f = floorf(sy0);
    float fy0 = sy0 - y0f;
    int r0 = (int)y0f;
    int r0c = min(max(r0, 0), H0 - 1), r1c = min(max(r0 + 1, 0), H0 - 1);

    float sy1 = (y + 0.5f) * 0.25f - 0.5f;
    float y1f = floorf(sy1);
    float fy1 = sy1 - y1f;
    int s0 = (int)y1f;
    int s0c = min(max(s0, 0), H1 - 1), s1c = min(max(s0 + 1, 0), H1 - 1);

    if (tid < W0) {
        float u = p0b[r0c * W0 + tid], v = p0b[r1c * W0 + tid];
        a0[tid] = u + fy0 * (v - u);
    }
    {
        float u = p1b[s0c * W1 + tid], v = p1b[s1c * W1 + tid];
        a1[tid] = u + fy1 * (v - u);
    }
    __syncthreads();

    float v0[4], v1[4];
#pragma unroll
    for (int i = 0; i < 4; ++i) {
        int x = tid * 4 + i;
        float sx0 = (x + 0.5f) * 0.125f - 0.5f;
        float x0f = floorf(sx0);
        float fx0 = sx0 - x0f;
        int c0 = (int)x0f;
        int c0c = min(max(c0, 0), W0 - 1), c1c = min(max(c0 + 1, 0), W0 - 1);
        float p0 = a0[c0c] + fx0 * (a0[c1c] - a0[c0c]);

        float sx1 = (x + 0.5f) * 0.25f - 0.5f;
        float x1f = floorf(sx1);
        float fx1 = sx1 - x1f;
        int d0 = (int)x1f;
        int d0c = min(max(d0, 0), W1 - 1), d1c = min(max(d0 + 1, 0), W1 - 1);
        float p1 = a1[d0c] + fx1 * (a1[d1c] - a1[d0c]);

        v0[i] = p0;
        v1[i] = p1 + p0;
    }
    const size_t NPXQ = (size_t)NB * IMH * IMW / 4;
    size_t t = (size_t)blk * 256 + tid;
    ((float4*)out)[t] = make_float4(v0[0], v0[1], v0[2], v0[3]);
    ((float4*)out)[NPXQ + t] = make_float4(v1[0], v1[1], v1[2], v1[3]);
}

// ---------------------------------------------------------------------------
extern "C" void kernel_launch(void* const* d_in, const int* in_sizes, int n_in,
                              void* d_out, int out_size, void* d_ws, size_t ws_size,
                              hipStream_t stream) {
    const float* fl0 = (const float*)d_in[0];
    const float* fr0 = (const float*)d_in[1];
    const float* fl1 = (const float*)d_in[2];
    const float* fr1 = (const float*)d_in[3];
    float* out = (float*)d_out;

    float* ws = (float*)d_ws;
    float* pl0 = ws;                 // 32768 floats
    float* pl1 = ws + 32768;         // 131072 floats

    k_main<<<NB * H0, 512, 0, stream>>>(fl0, fr0, fl1, fr1, pl0, pl1);
    k_final<<<NB * IMH, 256, 0, stream>>>(pl0, pl1, out);
}